// Round 1
// baseline (5998.706 us; speedup 1.0000x reference)
//
#include <hip/hip_runtime.h>

typedef long long ll;

#define NEGV -1e9f

// ---------------- static scratch (294 MiB) ----------------
// offsets (floats):
//  gx 0 (4194304) | glnx 4194304 | gkx 8388608 (262144) | glnk 8650752
//  gcl 8912896 (1024) | glnc 8913920 | gqx 8914944 (12582912)
//  gqk 21497856 (786432) | gqc 22284288 (3072) | gao 22287360 (4194304)
//  gko 26481664 (262144) | gco 26743808 (1024) | gsc 26744832 (16777216)
//  gkd 43522048 (16777216) | gh 60299264 (16777216) | total 77076480
__device__ float g_buf[77076480UL];

// ---------------- reduction helpers (block = 256 = 4 waves) ----------------
__device__ __forceinline__ float wave_sum(float v) {
#pragma unroll
  for (int o = 1; o < 64; o <<= 1) v += __shfl_xor(v, o, 64);
  return v;
}
__device__ __forceinline__ float wave_max(float v) {
#pragma unroll
  for (int o = 1; o < 64; o <<= 1) v = fmaxf(v, __shfl_xor(v, o, 64));
  return v;
}
__device__ __forceinline__ float block_sum(float v, float* red) {
  v = wave_sum(v);
  if ((threadIdx.x & 63) == 0) red[threadIdx.x >> 6] = v;
  __syncthreads();
  float r = red[0] + red[1] + red[2] + red[3];
  __syncthreads();
  return r;
}
__device__ __forceinline__ float block_max(float v, float* red) {
  v = wave_max(v);
  if ((threadIdx.x & 63) == 0) red[threadIdx.x >> 6] = v;
  __syncthreads();
  float r = fmaxf(fmaxf(red[0], red[1]), fmaxf(red[2], red[3]));
  __syncthreads();
  return r;
}

// ---------------- LayerNorm over rows of 512 ----------------
__global__ __launch_bounds__(256) void ln_kernel(
    const float* __restrict__ in, float* __restrict__ out,
    const float* __restrict__ gg, const float* __restrict__ bb) {
  __shared__ float red[4];
  size_t row = blockIdx.x;
  int tid = threadIdx.x;
  const float* p = in + row * 512;
  float v0 = p[tid], v1 = p[tid + 256];
  float mu = block_sum(v0 + v1, red) * (1.0f / 512.0f);
  float d0 = v0 - mu, d1 = v1 - mu;
  float var = block_sum(d0 * d0 + d1 * d1, red) * (1.0f / 512.0f);
  float rstd = rsqrtf(var + 1e-5f);
  out[row * 512 + tid] = d0 * rstd * gg[tid] + bb[tid];
  out[row * 512 + tid + 256] = d1 * rstd * gg[tid + 256] + bb[tid + 256];
}

// ---------------- generic strided-batched SGEMM ----------------
// C[z] = alpha * A[z] (Mr x K, lda) * B[z]  (+bias, +gelu, +residual)
// TRB: B is (Nc x K) row-major -> C = A*B^T, else B is (K x Nc)
// batch z = zo*innerB + zi, operand offsets zo*so + zi*si
template <bool TRB, bool BIAS, bool RES, bool GELU>
__global__ __launch_bounds__(256) void gemm_kernel(
    const float* __restrict__ A, const float* __restrict__ Bm,
    const float* __restrict__ bias, const float* __restrict__ R,
    float* __restrict__ C, int Mr, int Nc, int K, int lda, int ldb, int ldr,
    int ldc, ll soA, ll siA, ll soB, ll siB, ll soC, ll siC, int innerB,
    float alpha) {
  int zo = blockIdx.z / innerB, zi = blockIdx.z % innerB;
  A += zo * soA + zi * siA;
  Bm += zo * soB + zi * siB;
  C += zo * soC + zi * siC;
  __shared__ float As[16][65];
  __shared__ float Bs[16][65];
  int tid = threadIdx.x;
  int tx = tid & 15, ty = tid >> 4;
  int m0 = blockIdx.y * 64, n0 = blockIdx.x * 64;
  float acc[4][4] = {};
  for (int k0 = 0; k0 < K; k0 += 16) {
    {
      int m = tid >> 2, k4 = (tid & 3) << 2;
      int row = m0 + m;
      float4 v = make_float4(0.f, 0.f, 0.f, 0.f);
      if (row < Mr) v = *(const float4*)(A + (size_t)row * lda + k0 + k4);
      As[k4][m] = v.x; As[k4 + 1][m] = v.y; As[k4 + 2][m] = v.z; As[k4 + 3][m] = v.w;
    }
    if (TRB) {
      int n = tid >> 2, k4 = (tid & 3) << 2;
      float4 v = *(const float4*)(Bm + (size_t)(n0 + n) * ldb + k0 + k4);
      Bs[k4][n] = v.x; Bs[k4 + 1][n] = v.y; Bs[k4 + 2][n] = v.z; Bs[k4 + 3][n] = v.w;
    } else {
      int n = tid & 63, k = tid >> 6;
#pragma unroll
      for (int s = 0; s < 4; ++s)
        Bs[k + 4 * s][n] = Bm[(size_t)(k0 + k + 4 * s) * ldb + n0 + n];
    }
    __syncthreads();
#pragma unroll
    for (int kk = 0; kk < 16; ++kk) {
      float a[4], b[4];
#pragma unroll
      for (int i = 0; i < 4; ++i) a[i] = As[kk][ty * 4 + i];
#pragma unroll
      for (int j = 0; j < 4; ++j) b[j] = Bs[kk][tx * 4 + j];
#pragma unroll
      for (int i = 0; i < 4; ++i)
#pragma unroll
        for (int j = 0; j < 4; ++j) acc[i][j] = fmaf(a[i], b[j], acc[i][j]);
    }
    __syncthreads();
  }
#pragma unroll
  for (int i = 0; i < 4; ++i) {
    int row = m0 + ty * 4 + i;
    if (row < Mr) {
#pragma unroll
      for (int j = 0; j < 4; ++j) {
        int col = n0 + tx * 4 + j;
        float v = alpha * acc[i][j];
        if (BIAS) v += bias[col];
        if (GELU) v = 0.5f * v * (1.0f + erff(v * 0.70710678f));
        if (RES) v += R[(size_t)row * ldr + col];
        C[(size_t)row * ldc + col] = v;
      }
    }
  }
}

// ---------------- t-attention: dots, dual softmax, xrd, PV ----------------
// grid (N/32, B*H); block 256 (4 waves, each wave: 8 rows i)
__global__ __launch_bounds__(256) void tattn_kernel(
    const float* __restrict__ qx, const float* __restrict__ qk,
    const float* __restrict__ rd, const float* __restrict__ mask,
    const float* __restrict__ kmask, float* __restrict__ sc,
    float* __restrict__ ao) {
  __shared__ float ks[256][65];
  __shared__ float vs[256][64];
  __shared__ float qs[4][64];
  __shared__ float ws[4][256];
  __shared__ float kms[256];
  int bh = blockIdx.y, b = bh >> 3, h = bh & 7;
  int i0 = blockIdx.x * 32;
  int tid = threadIdx.x;
  for (int idx = tid; idx < 4096; idx += 256) {
    int j = idx >> 4, d4 = (idx & 15) << 2;
    const float* base = qk + (size_t)(b * 256 + j) * 1536 + h * 64 + d4;
    float4 kv = *(const float4*)(base + 512);
    ks[j][d4] = kv.x; ks[j][d4 + 1] = kv.y; ks[j][d4 + 2] = kv.z; ks[j][d4 + 3] = kv.w;
    float4 vv = *(const float4*)(base + 1024);
    vs[j][d4] = vv.x; vs[j][d4 + 1] = vv.y; vs[j][d4 + 2] = vv.z; vs[j][d4 + 3] = vv.w;
  }
  kms[tid] = kmask[b * 256 + tid];
  __syncthreads();
  int w = tid >> 6, lane = tid & 63;
  for (int t = 0; t < 8; ++t) {
    int i = i0 + w * 8 + t;
    qs[w][lane] = qx[(size_t)(b * 4096 + i) * 1536 + h * 64 + lane];
    float mi = mask[b * 4096 + i];
    float dotv[4];
#pragma unroll
    for (int s = 0; s < 4; ++s) {
      int j = lane + 64 * s;
      float acc = 0.f;
#pragma unroll
      for (int d = 0; d < 64; ++d) acc = fmaf(qs[w][d], ks[j][d], acc);
      dotv[s] = (mi * kms[j] < 0.5f) ? NEGV : acc * 0.125f;
    }
    float mx = fmaxf(fmaxf(dotv[0], dotv[1]), fmaxf(dotv[2], dotv[3]));
    mx = wave_max(mx);
    float e[4], es[4], Z = 0.f, Zs = 0.f;
#pragma unroll
    for (int s = 0; s < 4; ++s) {
      e[s] = expf(dotv[s] - mx);
      es[s] = expf(24.f * (dotv[s] - mx));
      Z += e[s];
      Zs += es[s];
    }
    Z = wave_sum(Z);
    Zs = wave_sum(Zs);
    float iZ = 1.f / Z, iZs = 1.f / Zs;
#pragma unroll
    for (int s = 0; s < 4; ++s) {
      int j = lane + 64 * s;
      float r = rd[((size_t)b * 256 + j) * 4096 + i];
      sc[((size_t)bh * 4096 + i) * 256 + j] = es[s] * iZs * r;
      ws[w][j] = e[s] * iZ * r;
    }
    float o = 0.f;
#pragma unroll 4
    for (int j = 0; j < 256; ++j) o = fmaf(ws[w][j], vs[j][lane], o);
    ao[(size_t)(b * 4096 + i) * 512 + h * 64 + lane] = o;
  }
}

// ---------------- cls-token attention (1 query row per (b,h)) ----------------
__global__ __launch_bounds__(256) void cattn_kernel(
    const float* __restrict__ qc, const float* __restrict__ qk,
    const float* __restrict__ mask, const float* __restrict__ kmask,
    float* __restrict__ co) {
  __shared__ float q[64];
  __shared__ float p[256];
  __shared__ float red[4];
  __shared__ float part[4][64];
  int bh = blockIdx.x, b = bh >> 3, h = bh & 7;
  int tid = threadIdx.x;
  if (tid < 64) q[tid] = qc[(size_t)b * 1536 + h * 64 + tid];
  __syncthreads();
  float dot = 0.f;
  {
    const float* kr = qk + (size_t)(b * 256 + tid) * 1536 + 512 + h * 64;
#pragma unroll
    for (int d = 0; d < 64; ++d) dot = fmaf(q[d], kr[d], dot);
  }
  float mk = mask[b * 4096] * kmask[b * 256 + tid];
  dot = (mk < 0.5f) ? NEGV : dot * 0.125f;
  float mx = block_max(dot, red);
  float e = expf(dot - mx);
  float Z = block_sum(e, red);
  p[tid] = e / Z;
  __syncthreads();
  int d = tid & 63, s = tid >> 6;
  float acc = 0.f;
  for (int j = s * 64; j < s * 64 + 64; ++j)
    acc = fmaf(p[j], qk[(size_t)(b * 256 + j) * 1536 + 1024 + h * 64 + d], acc);
  part[s][d] = acc;
  __syncthreads();
  if (tid < 64)
    co[(size_t)b * 512 + h * 64 + tid] =
        part[0][tid] + part[1][tid] + part[2][tid] + part[3][tid];
}

// ---------------- k-attention row softmax * rd (rows of 4096) ----------------
__global__ __launch_bounds__(256) void ksm_kernel(
    float* __restrict__ kd, const float* __restrict__ rd,
    const float* __restrict__ mask, const float* __restrict__ kmask) {
  __shared__ float red[4];
  int rowid = blockIdx.x;
  int bh = rowid >> 8, i = rowid & 255, b = bh >> 3;
  float* p = kd + (size_t)rowid * 4096;
  int tid = threadIdx.x;
  float km = kmask[b * 256 + i];
  float vals[16];
  float mx = -3.0e38f;
#pragma unroll
  for (int t = 0; t < 16; ++t) {
    int j = tid + 256 * t;
    float v = p[j];
    v = (mask[b * 4096 + j] * km < 0.5f) ? NEGV : v;
    vals[t] = v;
    mx = fmaxf(mx, v);
  }
  mx = block_max(mx, red);
  float sum = 0.f;
#pragma unroll
  for (int t = 0; t < 16; ++t) {
    vals[t] = expf(vals[t] - mx);
    sum += vals[t];
  }
  sum = block_sum(sum, red);
  float inv = 1.f / sum;
  const float* rrow = rd + ((size_t)b * 256 + i) * 4096;
#pragma unroll
  for (int t = 0; t < 16; ++t) {
    int j = tid + 256 * t;
    p[j] = vals[t] * inv * rrow[j];
  }
}

// ---------------- Sc (BH,N,M) -> amaps (BH,M,N) transpose ----------------
__global__ void trans_kernel(const float* __restrict__ src,
                             float* __restrict__ dst) {
  __shared__ float tile[32][33];
  int bh = blockIdx.z;
  int n0 = blockIdx.x * 32, m0 = blockIdx.y * 32;
  int tx = threadIdx.x, ty = threadIdx.y;
#pragma unroll
  for (int k = 0; k < 4; ++k)
    tile[ty + 8 * k][tx] =
        src[((size_t)bh * 4096 + n0 + ty + 8 * k) * 256 + m0 + tx];
  __syncthreads();
#pragma unroll
  for (int k = 0; k < 4; ++k)
    dst[((size_t)bh * 256 + m0 + ty + 8 * k) * 4096 + n0 + tx] =
        tile[tx][ty + 8 * k];
}

__global__ void kreps_kernel(const float* __restrict__ kx,
                             const float* __restrict__ kmask,
                             float* __restrict__ o) {
  int idx = blockIdx.x * 256 + threadIdx.x;
  float km = kmask[idx >> 9];
  o[idx] = (km < 0.5f) ? 0.f : kx[idx];
}

__global__ void clcopy_kernel(const float* __restrict__ s,
                              float* __restrict__ o) {
  int idx = blockIdx.x * 256 + threadIdx.x;
  o[idx] = s[idx];
}

// ---------------- host launcher ----------------
extern "C" void kernel_launch(void* const* d_in, const int* in_sizes, int n_in,
                              void* d_out, int out_size, void* d_ws,
                              size_t ws_size, hipStream_t stream) {
  const float* x = (const float*)d_in[0];
  const float* kx = (const float*)d_in[1];
  const float* rd = (const float*)d_in[2];
  const float* clst = (const float*)d_in[3];
  const float* mask = (const float*)d_in[4];
  const float* kmask = (const float*)d_in[5];
  const float* ln0g = (const float*)d_in[6];
  const float* ln0b = (const float*)d_in[7];
  const float* qkvw = (const float*)d_in[8];
  const float* outw = (const float*)d_in[9];
  const float* outb = (const float*)d_in[10];
  const float* ln1g = (const float*)d_in[11];
  const float* ln1b = (const float*)d_in[12];
  const float* fw1 = (const float*)d_in[13];
  const float* fb1 = (const float*)d_in[14];
  const float* fw2 = (const float*)d_in[15];
  const float* fb2 = (const float*)d_in[16];
  float* out = (float*)d_out;

  float* buf = nullptr;
  hipGetSymbolAddress((void**)&buf, HIP_SYMBOL(g_buf));
  float* gx = buf + 0UL;
  float* glnx = buf + 4194304UL;
  float* gkx = buf + 8388608UL;
  float* glnk = buf + 8650752UL;
  float* gcl = buf + 8912896UL;
  float* glnc = buf + 8913920UL;
  float* gqx = buf + 8914944UL;
  float* gqk = buf + 21497856UL;
  float* gqc = buf + 22284288UL;
  float* gao = buf + 22287360UL;
  float* gko = buf + 26481664UL;
  float* gco = buf + 26743808UL;
  float* gsc = buf + 26744832UL;
  float* gkd = buf + 43522048UL;
  float* gh = buf + 60299264UL;

  hipMemcpyAsync(gx, x, 4194304UL * 4, hipMemcpyDeviceToDevice, stream);
  hipMemcpyAsync(gkx, kx, 262144UL * 4, hipMemcpyDeviceToDevice, stream);
  hipMemcpyAsync(gcl, clst, 1024UL * 4, hipMemcpyDeviceToDevice, stream);

  for (int l = 0; l < 2; ++l) {
    const float* qw = qkvw + (size_t)l * 512 * 1536;
    const float* ow = outw + (size_t)l * 512 * 512;
    const float* ob = outb + (size_t)l * 512;
    const float* l0g = ln0g + l * 512;
    const float* l0b = ln0b + l * 512;
    const float* l1g = ln1g + l * 512;
    const float* l1b = ln1b + l * 512;
    const float* w1 = fw1 + (size_t)l * 512 * 2048;
    const float* b1 = fb1 + (size_t)l * 2048;
    const float* w2 = fw2 + (size_t)l * 2048 * 512;
    const float* b2 = fb2 + (size_t)l * 512;

    ln_kernel<<<8192, 256, 0, stream>>>(gx, glnx, l0g, l0b);
    ln_kernel<<<512, 256, 0, stream>>>(gkx, glnk, l0g, l0b);
    ln_kernel<<<2, 256, 0, stream>>>(gcl, glnc, l0g, l0b);

    gemm_kernel<false, false, false, false><<<dim3(24, 128, 1), 256, 0, stream>>>(
        glnx, qw, nullptr, nullptr, gqx, 8192, 1536, 512, 512, 1536, 0, 1536,
        0, 0, 0, 0, 0, 0, 1, 1.0f);
    gemm_kernel<false, false, false, false><<<dim3(24, 8, 1), 256, 0, stream>>>(
        glnk, qw, nullptr, nullptr, gqk, 512, 1536, 512, 512, 1536, 0, 1536,
        0, 0, 0, 0, 0, 0, 1, 1.0f);
    gemm_kernel<false, false, false, false><<<dim3(24, 1, 1), 256, 0, stream>>>(
        glnc, qw, nullptr, nullptr, gqc, 2, 1536, 512, 512, 1536, 0, 1536,
        0, 0, 0, 0, 0, 0, 1, 1.0f);

    tattn_kernel<<<dim3(128, 16, 1), 256, 0, stream>>>(gqx, gqk, rd, mask,
                                                       kmask, gsc, gao);
    cattn_kernel<<<16, 256, 0, stream>>>(gqc, gqk, mask, kmask, gco);

    gemm_kernel<true, false, false, false><<<dim3(64, 4, 16), 256, 0, stream>>>(
        gqk, gqx + 512, nullptr, nullptr, gkd, 256, 4096, 64, 1536, 1536, 0,
        4096, 393216LL, 64LL, 6291456LL, 64LL, 8388608LL, 1048576LL, 8, 0.125f);
    ksm_kernel<<<4096, 256, 0, stream>>>(gkd, rd, mask, kmask);
    gemm_kernel<false, false, false, false><<<dim3(1, 4, 16), 256, 0, stream>>>(
        gkd, gqx + 1024, nullptr, nullptr, gko, 256, 64, 4096, 4096, 1536, 0,
        512, 8388608LL, 1048576LL, 6291456LL, 64LL, 131072LL, 64LL, 8, 1.0f);

    gemm_kernel<false, true, true, false><<<dim3(8, 128, 1), 256, 0, stream>>>(
        gao, ow, ob, glnx, gx, 8192, 512, 512, 512, 512, 512, 512,
        0, 0, 0, 0, 0, 0, 1, 1.0f);
    gemm_kernel<false, true, true, false><<<dim3(8, 8, 1), 256, 0, stream>>>(
        gko, ow, ob, glnk, gkx, 512, 512, 512, 512, 512, 512, 512,
        0, 0, 0, 0, 0, 0, 1, 1.0f);
    gemm_kernel<false, true, true, false><<<dim3(8, 1, 1), 256, 0, stream>>>(
        gco, ow, ob, glnc, gcl, 2, 512, 512, 512, 512, 512, 512,
        0, 0, 0, 0, 0, 0, 1, 1.0f);

    // FF x
    ln_kernel<<<8192, 256, 0, stream>>>(gx, glnx, l1g, l1b);
    gemm_kernel<false, true, false, true><<<dim3(32, 128, 1), 256, 0, stream>>>(
        glnx, w1, b1, nullptr, gh, 8192, 2048, 512, 512, 2048, 0, 2048,
        0, 0, 0, 0, 0, 0, 1, 1.0f);
    gemm_kernel<false, true, true, false><<<dim3(8, 128, 1), 256, 0, stream>>>(
        gh, w2, b2, gx, gx, 8192, 512, 2048, 2048, 512, 512, 512,
        0, 0, 0, 0, 0, 0, 1, 1.0f);
    // FF kx
    ln_kernel<<<512, 256, 0, stream>>>(gkx, glnk, l1g, l1b);
    gemm_kernel<false, true, false, true><<<dim3(32, 8, 1), 256, 0, stream>>>(
        glnk, w1, b1, nullptr, gh, 512, 2048, 512, 512, 2048, 0, 2048,
        0, 0, 0, 0, 0, 0, 1, 1.0f);
    gemm_kernel<false, true, true, false><<<dim3(8, 8, 1), 256, 0, stream>>>(
        gh, w2, b2, gkx, gkx, 512, 512, 2048, 2048, 512, 512, 512,
        0, 0, 0, 0, 0, 0, 1, 1.0f);
    // FF clst
    ln_kernel<<<2, 256, 0, stream>>>(gcl, glnc, l1g, l1b);
    gemm_kernel<false, true, false, true><<<dim3(32, 1, 1), 256, 0, stream>>>(
        glnc, w1, b1, nullptr, gh, 2, 2048, 512, 512, 2048, 0, 2048,
        0, 0, 0, 0, 0, 0, 1, 1.0f);
    gemm_kernel<false, true, true, false><<<dim3(8, 1, 1), 256, 0, stream>>>(
        gh, w2, b2, gcl, gcl, 2, 512, 2048, 2048, 512, 512, 512,
        0, 0, 0, 0, 0, 0, 1, 1.0f);

    kreps_kernel<<<1024, 256, 0, stream>>>(gkx, kmask, out + (size_t)l * 262144);
    trans_kernel<<<dim3(128, 8, 16), dim3(32, 8, 1), 0, stream>>>(
        gsc, out + 525312UL + (size_t)l * 16777216UL);
  }
  clcopy_kernel<<<4, 256, 0, stream>>>(gcl, out + 524288UL);
}

// Round 2
// 2051.888 us; speedup vs baseline: 2.9235x; 2.9235x over previous
//
#include <hip/hip_runtime.h>

typedef long long ll;
typedef unsigned int uint;
typedef unsigned short ushort;
typedef __attribute__((ext_vector_type(8))) short short8;
typedef __attribute__((ext_vector_type(4))) float floatx4;

#define NEGV -1e9f

// ---------------- static scratch ----------------
// float offsets:
//  gx 0 (4194304) | glnx 4194304 | gkx 8388608 (262144) | glnk 8650752
//  gcl 8912896 (1024) | glnc 8913920 | gqx 8914944 (12582912)
//  gqk 21497856 (786432) | gqc 22284288 (3072) | gao 22287360 (4194304)
//  gko 26481664 (262144) | gco 26743808 (1024) | gsc 26744832 (16777216)
//  gkd 43522048 (16777216) | gh 60299264 (16777216)
//  grdT 77076480 (2097152) | wts 79173632 (3145728 fl = 6291456 ushort)
__device__ float g_buf[82319360UL];

__device__ __forceinline__ ushort f2bf(float f) {
  uint u = __float_as_uint(f);
  u += 0x7fffu + ((u >> 16) & 1u);
  return (ushort)(u >> 16);
}
__device__ __forceinline__ uint pack2(float lo, float hi) {
  return (uint)f2bf(lo) | ((uint)f2bf(hi) << 16);
}
__device__ __forceinline__ float bflo(uint u) { return __uint_as_float(u << 16); }
__device__ __forceinline__ float bfhi(uint u) { return __uint_as_float(u & 0xffff0000u); }

// ---------------- reductions ----------------
__device__ __forceinline__ float wave_sum(float v) {
#pragma unroll
  for (int o = 1; o < 64; o <<= 1) v += __shfl_xor(v, o, 64);
  return v;
}
__device__ __forceinline__ float wave_max(float v) {
#pragma unroll
  for (int o = 1; o < 64; o <<= 1) v = fmaxf(v, __shfl_xor(v, o, 64));
  return v;
}
__device__ __forceinline__ float block_sum(float v, float* red) {
  v = wave_sum(v);
  if ((threadIdx.x & 63) == 0) red[threadIdx.x >> 6] = v;
  __syncthreads();
  float r = red[0] + red[1] + red[2] + red[3];
  __syncthreads();
  return r;
}
__device__ __forceinline__ float block_max(float v, float* red) {
  v = wave_max(v);
  if ((threadIdx.x & 63) == 0) red[threadIdx.x >> 6] = v;
  __syncthreads();
  float r = fmaxf(fmaxf(red[0], red[1]), fmaxf(red[2], red[3]));
  __syncthreads();
  return r;
}

// ---------------- LayerNorm (rows of 512) ----------------
__global__ __launch_bounds__(256) void ln_kernel(
    const float* __restrict__ in, float* __restrict__ out,
    const float* __restrict__ gg, const float* __restrict__ bb) {
  __shared__ float red[4];
  size_t row = blockIdx.x;
  int tid = threadIdx.x;
  const float* p = in + row * 512;
  float v0 = p[tid], v1 = p[tid + 256];
  float mu = block_sum(v0 + v1, red) * (1.0f / 512.0f);
  float d0 = v0 - mu, d1 = v1 - mu;
  float var = block_sum(d0 * d0 + d1 * d1, red) * (1.0f / 512.0f);
  float rstd = rsqrtf(var + 1e-5f);
  out[row * 512 + tid] = d0 * rstd * gg[tid] + bb[tid];
  out[row * 512 + tid + 256] = d1 * rstd * gg[tid + 256] + bb[tid + 256];
}

// ---------------- generic fp32 batched transpose ----------------
// src (Z, R, C) -> dst (Z, C, R), 32x32 tiles, block (32,8)
__global__ void tposef(const float* __restrict__ src, float* __restrict__ dst,
                       int R, int C) {
  __shared__ float tile[32][33];
  int z = blockIdx.z;
  int c0 = blockIdx.x * 32, r0 = blockIdx.y * 32;
  int tx = threadIdx.x, ty = threadIdx.y;
  size_t base = (size_t)z * R * C;
#pragma unroll
  for (int k = 0; k < 4; ++k)
    tile[ty + 8 * k][tx] = src[base + (size_t)(r0 + ty + 8 * k) * C + c0 + tx];
  __syncthreads();
#pragma unroll
  for (int k = 0; k < 4; ++k)
    dst[base + (size_t)(c0 + ty + 8 * k) * R + r0 + tx] = tile[tx][ty + 8 * k];
}

// ---------------- fp32 (R,C) -> bf16 (C,R) weight transpose ----------------
__global__ void tposebf(const float* __restrict__ src, ushort* __restrict__ dst,
                        int R, int C) {
  __shared__ float tile[32][33];
  int c0 = blockIdx.x * 32, r0 = blockIdx.y * 32;
  int tx = threadIdx.x, ty = threadIdx.y;
#pragma unroll
  for (int k = 0; k < 4; ++k)
    tile[ty + 8 * k][tx] = src[(size_t)(r0 + ty + 8 * k) * C + c0 + tx];
  __syncthreads();
#pragma unroll
  for (int k = 0; k < 4; ++k)
    dst[(size_t)(c0 + ty + 8 * k) * R + r0 + tx] = f2bf(tile[tx][ty + 8 * k]);
}

// ---------------- bf16 MFMA GEMM ----------------
// C = alpha * A(M x K fp32, lda) * B + epilogue
// BMODE 0: B bf16 (N x K), ldb   (pre-transposed weights)
// BMODE 1: B fp32 (N x K), ldb
// BMODE 2: B fp32 (K x N), ldb  (transposed during staging)
// batch z: kslice = z % KS; zz = z / KS; zo = zz/innerB, zi = zz%innerB
template <int BMODE, bool BIAS, bool RES, bool GELU, bool ATOMIC>
__global__ __launch_bounds__(256) void mgemm(
    const float* __restrict__ A, const void* __restrict__ Bv,
    const float* __restrict__ bias, const float* __restrict__ R,
    float* __restrict__ C, int Mr, int Nc, int K, int lda, int ldb, int ldr,
    int ldc, ll soA, ll siA, ll soB, ll siB, ll soC, ll siC, int innerB,
    int KS, float alpha) {
  int kslice = blockIdx.z % KS;
  int zz = blockIdx.z / KS;
  int zo = zz / innerB, zi = zz % innerB;
  A += zo * soA + zi * siA;
  C += zo * soC + zi * siC;
  const float* Bf = (const float*)Bv + zo * soB + zi * siB;
  const ushort* Bh = (const ushort*)Bv + zo * soB + zi * siB;
  __shared__ ushort As[128 * 40];
  __shared__ ushort Bs[128 * 40];
  int tid = threadIdx.x;
  int m0 = blockIdx.y * 128, n0 = blockIdx.x * 128;
  int w = tid >> 6, lane = tid & 63;
  int ml = lane & 15, quad = lane >> 4;
  int m0w = (w & 1) * 64, n0w = (w >> 1) * 64;
  floatx4 acc[4][4];
#pragma unroll
  for (int i = 0; i < 4; ++i)
#pragma unroll
    for (int j = 0; j < 4; ++j)
#pragma unroll
      for (int e = 0; e < 4; ++e) acc[i][j][e] = 0.f;

  int Kper = K / KS;
  int kbeg = kslice * Kper, kend = kbeg + Kper;
  int sr = tid >> 1, skh = (tid & 1) << 4;  // staging: row/n, k-offset

  for (int k0 = kbeg; k0 < kend; k0 += 32) {
    // ---- stage A (fp32 -> bf16) ----
    {
      float f[16];
      int grow = m0 + sr;
      if (grow < Mr) {
        const float4* p = (const float4*)(A + (size_t)grow * lda + k0 + skh);
        float4 v0 = p[0], v1 = p[1], v2 = p[2], v3 = p[3];
        f[0] = v0.x; f[1] = v0.y; f[2] = v0.z; f[3] = v0.w;
        f[4] = v1.x; f[5] = v1.y; f[6] = v1.z; f[7] = v1.w;
        f[8] = v2.x; f[9] = v2.y; f[10] = v2.z; f[11] = v2.w;
        f[12] = v3.x; f[13] = v3.y; f[14] = v3.z; f[15] = v3.w;
      } else {
#pragma unroll
        for (int e = 0; e < 16; ++e) f[e] = 0.f;
      }
      uint* du = (uint*)(As + sr * 40 + skh);
#pragma unroll
      for (int e = 0; e < 8; ++e) du[e] = pack2(f[2 * e], f[2 * e + 1]);
    }
    // ---- stage B ----
    if (BMODE == 0) {
      uint4 v0 = make_uint4(0, 0, 0, 0), v1 = v0;
      if (n0 + sr < Nc) {
        const uint4* p = (const uint4*)(Bh + (size_t)(n0 + sr) * ldb + k0 + skh);
        v0 = p[0]; v1 = p[1];
      }
      uint4* d = (uint4*)(Bs + sr * 40 + skh);
      d[0] = v0; d[1] = v1;
    } else if (BMODE == 1) {
      float f[16];
      if (n0 + sr < Nc) {
        const float4* p = (const float4*)(Bf + (size_t)(n0 + sr) * ldb + k0 + skh);
        float4 v0 = p[0], v1 = p[1], v2 = p[2], v3 = p[3];
        f[0] = v0.x; f[1] = v0.y; f[2] = v0.z; f[3] = v0.w;
        f[4] = v1.x; f[5] = v1.y; f[6] = v1.z; f[7] = v1.w;
        f[8] = v2.x; f[9] = v2.y; f[10] = v2.z; f[11] = v2.w;
        f[12] = v3.x; f[13] = v3.y; f[14] = v3.z; f[15] = v3.w;
      } else {
#pragma unroll
        for (int e = 0; e < 16; ++e) f[e] = 0.f;
      }
      uint* du = (uint*)(Bs + sr * 40 + skh);
#pragma unroll
      for (int e = 0; e < 8; ++e) du[e] = pack2(f[2 * e], f[2 * e + 1]);
    } else {
      int kk = tid >> 3, n4 = (tid & 7) << 4;
      float f[16];
      if (n0 + n4 < Nc) {
        const float4* p = (const float4*)(Bf + (size_t)(k0 + kk) * ldb + n0 + n4);
        float4 v0 = p[0], v1 = p[1], v2 = p[2], v3 = p[3];
        f[0] = v0.x; f[1] = v0.y; f[2] = v0.z; f[3] = v0.w;
        f[4] = v1.x; f[5] = v1.y; f[6] = v1.z; f[7] = v1.w;
        f[8] = v2.x; f[9] = v2.y; f[10] = v2.z; f[11] = v2.w;
        f[12] = v3.x; f[13] = v3.y; f[14] = v3.z; f[15] = v3.w;
      } else {
#pragma unroll
        for (int e = 0; e < 16; ++e) f[e] = 0.f;
      }
#pragma unroll
      for (int e = 0; e < 16; ++e) Bs[(n4 + e) * 40 + kk] = f2bf(f[e]);
    }
    __syncthreads();
    short8 a[4], b[4];
#pragma unroll
    for (int i = 0; i < 4; ++i)
      a[i] = *(const short8*)(As + (m0w + i * 16 + ml) * 40 + quad * 8);
#pragma unroll
    for (int j = 0; j < 4; ++j)
      b[j] = *(const short8*)(Bs + (n0w + j * 16 + ml) * 40 + quad * 8);
#pragma unroll
    for (int i = 0; i < 4; ++i)
#pragma unroll
      for (int j = 0; j < 4; ++j)
        acc[i][j] = __builtin_amdgcn_mfma_f32_16x16x32_bf16(a[i], b[j],
                                                            acc[i][j], 0, 0, 0);
    __syncthreads();
  }
  // ---- epilogue ----
#pragma unroll
  for (int i = 0; i < 4; ++i) {
#pragma unroll
    for (int r = 0; r < 4; ++r) {
      int row = m0 + m0w + i * 16 + quad * 4 + r;
      if (row < Mr) {
#pragma unroll
        for (int j = 0; j < 4; ++j) {
          int col = n0 + n0w + j * 16 + ml;
          if (col < Nc) {
            float v = alpha * acc[i][j][r];
            if (ATOMIC) {
              unsafeAtomicAdd(&C[(size_t)row * ldc + col], v);
            } else {
              if (BIAS) v += bias[col];
              if (GELU) v = 0.5f * v * (1.0f + erff(v * 0.70710678f));
              if (RES) v += R[(size_t)row * ldr + col];
              C[(size_t)row * ldc + col] = v;
            }
          }
        }
      }
    }
  }
}

// ---------------- t-attention (restructured, fma-bound) ----------------
// grid (N/128, B*H), block 256. Each wave: 8 rows x 4 passes.
__global__ __launch_bounds__(256) void tattn_kernel(
    const float* __restrict__ qx, const float* __restrict__ qk,
    const float* __restrict__ rdT, const float* __restrict__ mask,
    const float* __restrict__ kmask, float* __restrict__ sc,
    float* __restrict__ ao) {
  __shared__ ushort ks[256 * 66];   // bf16 K, packed pairs; 33 uints/row
  __shared__ float vs[256 * 64];    // fp32 V
  __shared__ float ws8[4][8][256];  // probs per wave/row
  __shared__ float qs8[4][8][64];   // q rows per wave
  __shared__ float kms[256];
  int bh = blockIdx.y, b = bh >> 3, h = bh & 7;
  int i00 = blockIdx.x * 128;
  int tid = threadIdx.x;
  uint* ksu = (uint*)ks;
  // ---- stage K (bf16) + V (fp32) ----
  {
    int jr = tid >> 2, c = tid & 3;  // 64 rows per pass, 16 floats per thread
#pragma unroll
    for (int p = 0; p < 4; ++p) {
      int j = p * 64 + jr;
      const float* base = qk + (size_t)(b * 256 + j) * 1536 + h * 64 + c * 16;
      const float4* kp = (const float4*)(base + 512);
      float4 k0 = kp[0], k1 = kp[1], k2 = kp[2], k3 = kp[3];
      uint* kd = ksu + j * 33 + c * 8;
      kd[0] = pack2(k0.x, k0.y); kd[1] = pack2(k0.z, k0.w);
      kd[2] = pack2(k1.x, k1.y); kd[3] = pack2(k1.z, k1.w);
      kd[4] = pack2(k2.x, k2.y); kd[5] = pack2(k2.z, k2.w);
      kd[6] = pack2(k3.x, k3.y); kd[7] = pack2(k3.z, k3.w);
      const float4* vp = (const float4*)(base + 1024);
      float4* vd = (float4*)(vs + j * 64 + c * 16);
      vd[0] = vp[0]; vd[1] = vp[1]; vd[2] = vp[2]; vd[3] = vp[3];
    }
  }
  kms[tid] = kmask[b * 256 + tid];
  __syncthreads();
  int w = tid >> 6, lane = tid & 63;
  for (int pass = 0; pass < 4; ++pass) {
    int i0 = i00 + pass * 32 + w * 8;
    // q rows -> LDS (wave-local)
#pragma unroll
    for (int r = 0; r < 8; ++r)
      qs8[w][r][lane] = qx[(size_t)(b * 4096 + i0 + r) * 1536 + h * 64 + lane];
    // ---- dots: 8 rows x 4 cols per lane ----
    float dt[8][4];
#pragma unroll
    for (int r = 0; r < 8; ++r)
#pragma unroll
      for (int s = 0; s < 4; ++s) dt[r][s] = 0.f;
    for (int d4 = 0; d4 < 16; ++d4) {
      float4 qv[8];
#pragma unroll
      for (int r = 0; r < 8; ++r)
        qv[r] = ((const float4*)qs8[w][r])[d4];
#pragma unroll
      for (int s = 0; s < 4; ++s) {
        int j = lane + 64 * s;
        uint u0 = ksu[j * 33 + d4 * 2], u1 = ksu[j * 33 + d4 * 2 + 1];
        float k0 = bflo(u0), k1 = bfhi(u0), k2 = bflo(u1), k3 = bfhi(u1);
#pragma unroll
        for (int r = 0; r < 8; ++r) {
          dt[r][s] = fmaf(qv[r].x, k0, dt[r][s]);
          dt[r][s] = fmaf(qv[r].y, k1, dt[r][s]);
          dt[r][s] = fmaf(qv[r].z, k2, dt[r][s]);
          dt[r][s] = fmaf(qv[r].w, k3, dt[r][s]);
        }
      }
    }
    // ---- softmax (both temps) + rd, write sc + ws8 ----
#pragma unroll
    for (int r = 0; r < 8; ++r) {
      int i = i0 + r;
      float mi = mask[b * 4096 + i];
      float mx = -3.0e38f;
#pragma unroll
      for (int s = 0; s < 4; ++s) {
        int j = lane + 64 * s;
        float v = (mi * kms[j] < 0.5f) ? NEGV : dt[r][s] * 0.125f;
        dt[r][s] = v;
        mx = fmaxf(mx, v);
      }
      mx = wave_max(mx);
      float e[4], es[4], Z = 0.f, Zs = 0.f;
#pragma unroll
      for (int s = 0; s < 4; ++s) {
        e[s] = __expf(dt[r][s] - mx);
        es[s] = __expf(24.f * (dt[r][s] - mx));
        Z += e[s];
        Zs += es[s];
      }
      Z = wave_sum(Z);
      Zs = wave_sum(Zs);
      float iZ = 1.f / Z, iZs = 1.f / Zs;
#pragma unroll
      for (int s = 0; s < 4; ++s) {
        int j = lane + 64 * s;
        float rv = rdT[((size_t)b * 4096 + i) * 256 + j];
        sc[((size_t)bh * 4096 + i) * 256 + j] = es[s] * iZs * rv;
        ws8[w][r][j] = e[s] * iZ * rv;
      }
    }
    // ---- PV: o[r][lane] = sum_j ws8[r][j] * vs[j][lane] ----
    float o[8];
#pragma unroll
    for (int r = 0; r < 8; ++r) o[r] = 0.f;
    for (int jc = 0; jc < 64; ++jc) {
      int j = jc * 4;
      float v0 = vs[j * 64 + lane];
      float v1 = vs[(j + 1) * 64 + lane];
      float v2 = vs[(j + 2) * 64 + lane];
      float v3 = vs[(j + 3) * 64 + lane];
#pragma unroll
      for (int r = 0; r < 8; ++r) {
        float4 wv = ((const float4*)ws8[w][r])[jc];
        o[r] = fmaf(wv.x, v0, o[r]);
        o[r] = fmaf(wv.y, v1, o[r]);
        o[r] = fmaf(wv.z, v2, o[r]);
        o[r] = fmaf(wv.w, v3, o[r]);
      }
    }
#pragma unroll
    for (int r = 0; r < 8; ++r)
      ao[(size_t)(b * 4096 + i0 + r) * 512 + h * 64 + lane] = o[r];
  }
}

// ---------------- cls-token attention ----------------
__global__ __launch_bounds__(256) void cattn_kernel(
    const float* __restrict__ qc, const float* __restrict__ qk,
    const float* __restrict__ mask, const float* __restrict__ kmask,
    float* __restrict__ co) {
  __shared__ float q[64];
  __shared__ float p[256];
  __shared__ float red[4];
  __shared__ float part[4][64];
  int bh = blockIdx.x, b = bh >> 3, h = bh & 7;
  int tid = threadIdx.x;
  if (tid < 64) q[tid] = qc[(size_t)b * 1536 + h * 64 + tid];
  __syncthreads();
  float dot = 0.f;
  {
    const float* kr = qk + (size_t)(b * 256 + tid) * 1536 + 512 + h * 64;
#pragma unroll
    for (int d = 0; d < 64; ++d) dot = fmaf(q[d], kr[d], dot);
  }
  float mk = mask[b * 4096] * kmask[b * 256 + tid];
  dot = (mk < 0.5f) ? NEGV : dot * 0.125f;
  float mx = block_max(dot, red);
  float e = expf(dot - mx);
  float Z = block_sum(e, red);
  p[tid] = e / Z;
  __syncthreads();
  int d = tid & 63, s = tid >> 6;
  float acc = 0.f;
  for (int j = s * 64; j < s * 64 + 64; ++j)
    acc = fmaf(p[j], qk[(size_t)(b * 256 + j) * 1536 + 1024 + h * 64 + d], acc);
  part[s][d] = acc;
  __syncthreads();
  if (tid < 64)
    co[(size_t)b * 512 + h * 64 + tid] =
        part[0][tid] + part[1][tid] + part[2][tid] + part[3][tid];
}

// ---------------- k-attention row softmax * rd (rows of 4096) ----------------
__global__ __launch_bounds__(256) void ksm_kernel(
    float* __restrict__ kd, const float* __restrict__ rd,
    const float* __restrict__ mask, const float* __restrict__ kmask) {
  __shared__ float red[4];
  int rowid = blockIdx.x;
  int bh = rowid >> 8, i = rowid & 255, b = bh >> 3;
  float* p = kd + (size_t)rowid * 4096;
  int tid = threadIdx.x;
  float km = kmask[b * 256 + i];
  float vals[16];
  float mx = -3.0e38f;
#pragma unroll
  for (int t = 0; t < 16; ++t) {
    int j = tid + 256 * t;
    float v = p[j];
    v = (mask[b * 4096 + j] * km < 0.5f) ? NEGV : v;
    vals[t] = v;
    mx = fmaxf(mx, v);
  }
  mx = block_max(mx, red);
  float sum = 0.f;
#pragma unroll
  for (int t = 0; t < 16; ++t) {
    vals[t] = __expf(vals[t] - mx);
    sum += vals[t];
  }
  sum = block_sum(sum, red);
  float inv = 1.f / sum;
  const float* rrow = rd + ((size_t)b * 256 + i) * 4096;
#pragma unroll
  for (int t = 0; t < 16; ++t) {
    int j = tid + 256 * t;
    p[j] = vals[t] * inv * rrow[j];
  }
}

__global__ void kreps_kernel(const float* __restrict__ kx,
                             const float* __restrict__ kmask,
                             float* __restrict__ o) {
  int idx = blockIdx.x * 256 + threadIdx.x;
  float km = kmask[idx >> 9];
  o[idx] = (km < 0.5f) ? 0.f : kx[idx];
}

__global__ void clcopy_kernel(const float* __restrict__ s,
                              float* __restrict__ o) {
  int idx = blockIdx.x * 256 + threadIdx.x;
  o[idx] = s[idx];
}

// ---------------- host launcher ----------------
extern "C" void kernel_launch(void* const* d_in, const int* in_sizes, int n_in,
                              void* d_out, int out_size, void* d_ws,
                              size_t ws_size, hipStream_t stream) {
  const float* x = (const float*)d_in[0];
  const float* kx = (const float*)d_in[1];
  const float* rd = (const float*)d_in[2];
  const float* clst = (const float*)d_in[3];
  const float* mask = (const float*)d_in[4];
  const float* kmask = (const float*)d_in[5];
  const float* ln0g = (const float*)d_in[6];
  const float* ln0b = (const float*)d_in[7];
  const float* qkvw = (const float*)d_in[8];
  const float* outw = (const float*)d_in[9];
  const float* outb = (const float*)d_in[10];
  const float* ln1g = (const float*)d_in[11];
  const float* ln1b = (const float*)d_in[12];
  const float* fw1 = (const float*)d_in[13];
  const float* fb1 = (const float*)d_in[14];
  const float* fw2 = (const float*)d_in[15];
  const float* fb2 = (const float*)d_in[16];
  float* out = (float*)d_out;

  float* buf = nullptr;
  hipGetSymbolAddress((void**)&buf, HIP_SYMBOL(g_buf));
  float* gx = buf + 0UL;
  float* glnx = buf + 4194304UL;
  float* gkx = buf + 8388608UL;
  float* glnk = buf + 8650752UL;
  float* gcl = buf + 8912896UL;
  float* glnc = buf + 8913920UL;
  float* gqx = buf + 8914944UL;
  float* gqk = buf + 21497856UL;
  float* gqc = buf + 22284288UL;
  float* gao = buf + 22287360UL;
  float* gko = buf + 26481664UL;
  float* gco = buf + 26743808UL;
  float* gsc = buf + 26744832UL;
  float* gkd = buf + 43522048UL;
  float* gh = buf + 60299264UL;
  float* grdT = buf + 77076480UL;
  ushort* wts = (ushort*)(buf + 79173632UL);

  hipMemcpyAsync(gx, x, 4194304UL * 4, hipMemcpyDeviceToDevice, stream);
  hipMemcpyAsync(gkx, kx, 262144UL * 4, hipMemcpyDeviceToDevice, stream);
  hipMemcpyAsync(gcl, clst, 1024UL * 4, hipMemcpyDeviceToDevice, stream);

  // rd (b,256,4096) -> grdT (b,4096,256)
  tposef<<<dim3(128, 8, 2), dim3(32, 8, 1), 0, stream>>>(rd, grdT, 256, 4096);

  // weight convert+transpose: fp32 (K,N) -> bf16 (N,K)
  for (int l = 0; l < 2; ++l) {
    ushort* wtl = wts + (size_t)l * 3145728;
    tposebf<<<dim3(48, 16, 1), dim3(32, 8, 1), 0, stream>>>(
        qkvw + (size_t)l * 786432, wtl + 0, 512, 1536);
    tposebf<<<dim3(16, 16, 1), dim3(32, 8, 1), 0, stream>>>(
        outw + (size_t)l * 262144, wtl + 786432, 512, 512);
    tposebf<<<dim3(64, 16, 1), dim3(32, 8, 1), 0, stream>>>(
        fw1 + (size_t)l * 1048576, wtl + 1048576, 512, 2048);
    tposebf<<<dim3(16, 64, 1), dim3(32, 8, 1), 0, stream>>>(
        fw2 + (size_t)l * 1048576, wtl + 2097152, 2048, 512);
  }

  for (int l = 0; l < 2; ++l) {
    ushort* wtl = wts + (size_t)l * 3145728;
    ushort* qwt = wtl + 0;        // 1536 x 512
    ushort* owt = wtl + 786432;   // 512 x 512
    ushort* w1t = wtl + 1048576;  // 2048 x 512
    ushort* w2t = wtl + 2097152;  // 512 x 2048
    const float* ob = outb + (size_t)l * 512;
    const float* l0g = ln0g + l * 512;
    const float* l0b = ln0b + l * 512;
    const float* l1g = ln1g + l * 512;
    const float* l1b = ln1b + l * 512;
    const float* b1 = fb1 + (size_t)l * 2048;
    const float* b2 = fb2 + (size_t)l * 512;

    ln_kernel<<<8192, 256, 0, stream>>>(gx, glnx, l0g, l0b);
    ln_kernel<<<512, 256, 0, stream>>>(gkx, glnk, l0g, l0b);
    ln_kernel<<<2, 256, 0, stream>>>(gcl, glnc, l0g, l0b);

    // qkv projections
    mgemm<0, false, false, false, false><<<dim3(12, 64, 1), 256, 0, stream>>>(
        glnx, qwt, nullptr, nullptr, gqx, 8192, 1536, 512, 512, 512, 0, 1536,
        0, 0, 0, 0, 0, 0, 1, 1, 1.0f);
    mgemm<0, false, false, false, false><<<dim3(12, 4, 1), 256, 0, stream>>>(
        glnk, qwt, nullptr, nullptr, gqk, 512, 1536, 512, 512, 512, 0, 1536,
        0, 0, 0, 0, 0, 0, 1, 1, 1.0f);
    mgemm<0, false, false, false, false><<<dim3(12, 1, 1), 256, 0, stream>>>(
        glnc, qwt, nullptr, nullptr, gqc, 2, 1536, 512, 512, 512, 0, 1536,
        0, 0, 0, 0, 0, 0, 1, 1, 1.0f);

    tattn_kernel<<<dim3(32, 16, 1), 256, 0, stream>>>(gqx, gqk, grdT, mask,
                                                      kmask, gsc, gao);
    cattn_kernel<<<16, 256, 0, stream>>>(gqc, gqk, mask, kmask, gco);

    // k_dots = k_q @ t_k^T * scale  (per b,h)
    mgemm<1, false, false, false, false><<<dim3(32, 2, 16), 256, 0, stream>>>(
        gqk, gqx + 512, nullptr, nullptr, gkd, 256, 4096, 64, 1536, 1536, 0,
        4096, 393216LL, 64LL, 6291456LL, 64LL, 8388608LL, 1048576LL, 8, 1,
        0.125f);
    ksm_kernel<<<4096, 256, 0, stream>>>(gkd, rd, mask, kmask);
    // k_out = k_attn @ t_v  (split-K=8, atomic accumulate)
    hipMemsetAsync(gko, 0, 262144UL * 4, stream);
    mgemm<2, false, false, false, true><<<dim3(1, 2, 128), 256, 0, stream>>>(
        gkd, gqx + 1024, nullptr, nullptr, gko, 256, 64, 4096, 4096, 1536, 0,
        512, 8388608LL, 1048576LL, 6291456LL, 64LL, 131072LL, 64LL, 8, 8,
        1.0f);

    // to_out + residual
    mgemm<0, true, true, false, false><<<dim3(4, 64, 1), 256, 0, stream>>>(
        gao, owt, ob, glnx, gx, 8192, 512, 512, 512, 512, 512, 512,
        0, 0, 0, 0, 0, 0, 1, 1, 1.0f);
    mgemm<0, true, true, false, false><<<dim3(4, 4, 1), 256, 0, stream>>>(
        gko, owt, ob, glnk, gkx, 512, 512, 512, 512, 512, 512, 512,
        0, 0, 0, 0, 0, 0, 1, 1, 1.0f);
    mgemm<0, true, true, false, false><<<dim3(4, 1, 1), 256, 0, stream>>>(
        gco, owt, ob, glnc, gcl, 2, 512, 512, 512, 512, 512, 512,
        0, 0, 0, 0, 0, 0, 1, 1, 1.0f);

    // FF x
    ln_kernel<<<8192, 256, 0, stream>>>(gx, glnx, l1g, l1b);
    mgemm<0, true, false, true, false><<<dim3(16, 64, 1), 256, 0, stream>>>(
        glnx, w1t, b1, nullptr, gh, 8192, 2048, 512, 512, 512, 0, 2048,
        0, 0, 0, 0, 0, 0, 1, 1, 1.0f);
    mgemm<0, true, true, false, false><<<dim3(4, 64, 1), 256, 0, stream>>>(
        gh, w2t, b2, gx, gx, 8192, 512, 2048, 2048, 2048, 512, 512,
        0, 0, 0, 0, 0, 0, 1, 1, 1.0f);
    // FF kx
    ln_kernel<<<512, 256, 0, stream>>>(gkx, glnk, l1g, l1b);
    mgemm<0, true, false, true, false><<<dim3(16, 4, 1), 256, 0, stream>>>(
        glnk, w1t, b1, nullptr, gh, 512, 2048, 512, 512, 512, 0, 2048,
        0, 0, 0, 0, 0, 0, 1, 1, 1.0f);
    mgemm<0, true, true, false, false><<<dim3(4, 4, 1), 256, 0, stream>>>(
        gh, w2t, b2, gkx, gkx, 512, 512, 2048, 2048, 2048, 512, 512,
        0, 0, 0, 0, 0, 0, 1, 1, 1.0f);
    // FF clst
    ln_kernel<<<2, 256, 0, stream>>>(gcl, glnc, l1g, l1b);
    mgemm<0, true, false, true, false><<<dim3(16, 1, 1), 256, 0, stream>>>(
        glnc, w1t, b1, nullptr, gh, 2, 2048, 512, 512, 512, 0, 2048,
        0, 0, 0, 0, 0, 0, 1, 1, 1.0f);
    mgemm<0, true, true, false, false><<<dim3(4, 1, 1), 256, 0, stream>>>(
        gh, w2t, b2, gcl, gcl, 2, 512, 2048, 2048, 2048, 512, 512,
        0, 0, 0, 0, 0, 0, 1, 1, 1.0f);

    kreps_kernel<<<1024, 256, 0, stream>>>(gkx, kmask, out + (size_t)l * 262144);
    tposef<<<dim3(8, 128, 16), dim3(32, 8, 1), 0, stream>>>(
        gsc, out + 525312UL + (size_t)l * 16777216UL, 4096, 256);
  }
  clcopy_kernel<<<4, 256, 0, stream>>>(gcl, out + 524288UL);
}